// Round 2
// baseline (263.532 us; speedup 1.0000x reference)
//
#include <hip/hip_runtime.h>
#include <hip/hip_bf16.h>

// out = X + s*(relu(A_hat @ (X @ W_agg)) - X), s = sigmoid(wg)*sigmoid(wl)
// X[8192,256] f32, A_hat[8192,8192] f32, W[256,256] f32. Out f32 [8192,256].
// A (268MB, read once) dominates: HBM-bound, floor ~43us. Main GEMM streams A
// via global_load_lds with a 3-buffer ring + counted vmcnt (loads in flight
// across raw s_barriers), BN=256 so A is read exactly once.

typedef __attribute__((ext_vector_type(4))) float f32x4;
typedef __attribute__((ext_vector_type(8))) __bf16 bf16x8;

#define GLOBAL_AS __attribute__((address_space(1)))
#define LDS_AS __attribute__((address_space(3)))

static __device__ __forceinline__ void gload16(const void* g, void* l) {
  __builtin_amdgcn_global_load_lds((const GLOBAL_AS void*)g, (LDS_AS void*)l, 16, 0, 0);
}
// NT hint (CPol bit1) for the zero-reuse A stream: don't evict B/X/out from L2.
static __device__ __forceinline__ void gload16_nt(const void* g, void* l) {
  __builtin_amdgcn_global_load_lds((const GLOBAL_AS void*)g, (LDS_AS void*)l, 16, 0, 2);
}

static __device__ __forceinline__ unsigned short f2bf_bits(float f) {
  __bf16 h = (__bf16)f;
  return __builtin_bit_cast(unsigned short, h);
}

// ---------------- prep: s vector + W^T (bf16, tiled [k/32][n=256][32]) -------------
__global__ void prep_kernel(const float* __restrict__ W,
                            const float* __restrict__ wg,
                            const float* __restrict__ wl,
                            unsigned short* __restrict__ WT,  // [8][256][32] bf16
                            float* __restrict__ s) {
  int tid = blockIdx.x * 256 + threadIdx.x;  // 0..65535
  int k = tid >> 8, n = tid & 255;
  float w = W[tid];  // W[k][n]
  int kt = k >> 5, kloc = k & 31;
  WT[kt * 8192 + n * 32 + kloc] = f2bf_bits(w);
  if (tid < 8192) {
    float sg = 1.0f / (1.0f + expf(-wg[0]));
    float sl = 1.0f / (1.0f + expf(-wl[tid]));
    s[tid] = sg * sl;
  }
}

// ---------------- gemm0: XW = X @ W, write XW^T bf16 tiled [k/32][n=256][32] -------
// (unchanged from round 0 — verified correct, ~small cost)
__global__ __launch_bounds__(256, 2) void gemm_xw(
    const float* __restrict__ X,              // [8192][256]
    const unsigned short* __restrict__ WT,    // tiled [8][256][32]
    unsigned short* __restrict__ XWT) {       // tiled [256][256][32]
  __shared__ float As[2][32 * 32];
  __shared__ unsigned short Bs[2][128 * 32];

  const int bm = blockIdx.x & 255;
  const int bn = blockIdx.x >> 8;
  const int m0 = bm * 32;
  const int tid = threadIdx.x;
  const int w = tid >> 6;
  const int l = tid & 63;
  const int lr = l & 15;
  const int lq = l >> 4;

  const int pA = w * 1024 + l * 16;
  const int rA = pA >> 7;
  const int qA = (pA >> 4) & 7;
  const int ssA = qA ^ (rA & 7);
  const char* Asrc0 = (const char*)X + (size_t)(m0 + rA) * 1024 + ssA * 16;
  const char* Bsrc0 = (const char*)WT + bn * 8192 + w * 2048 + l * 16;

  f32x4 acc[2][2];
#pragma unroll
  for (int i = 0; i < 2; ++i)
#pragma unroll
    for (int j = 0; j < 2; ++j) acc[i][j] = (f32x4){0.f, 0.f, 0.f, 0.f};

  auto stage = [&](int t, int buf) {
    gload16(Asrc0 + (size_t)t * 128, (char*)&As[buf][0] + w * 1024);
    const char* bs = Bsrc0 + (size_t)t * 16384;
    gload16(bs, (char*)&Bs[buf][0] + w * 2048);
    gload16(bs + 1024, (char*)&Bs[buf][0] + w * 2048 + 1024);
  };

  auto compute = [&](int buf) {
    bf16x8 af[2];
#pragma unroll
    for (int mi = 0; mi < 2; ++mi) {
      int r = mi * 16 + lr;
      const float* ap = &As[buf][r * 32];
      int s0 = (2 * lq) ^ (r & 7);
      int s1 = (2 * lq + 1) ^ (r & 7);
      f32x4 a0 = *(const f32x4*)(ap + s0 * 4);
      f32x4 a1 = *(const f32x4*)(ap + s1 * 4);
      bf16x8 v;
      v[0] = (__bf16)a0.x; v[1] = (__bf16)a0.y; v[2] = (__bf16)a0.z; v[3] = (__bf16)a0.w;
      v[4] = (__bf16)a1.x; v[5] = (__bf16)a1.y; v[6] = (__bf16)a1.z; v[7] = (__bf16)a1.w;
      af[mi] = v;
    }
    bf16x8 bfr[2];
#pragma unroll
    for (int ni = 0; ni < 2; ++ni) {
      int row = w * 32 + ni * 16 + lr;
      bfr[ni] = *(const bf16x8*)(&Bs[buf][row * 32 + lq * 8]);
    }
#pragma unroll
    for (int mi = 0; mi < 2; ++mi)
#pragma unroll
      for (int ni = 0; ni < 2; ++ni)
        acc[mi][ni] = __builtin_amdgcn_mfma_f32_16x16x32_bf16(af[mi], bfr[ni], acc[mi][ni], 0, 0, 0);
  };

  stage(0, 0);
  __syncthreads();
  for (int t = 0; t < 8; ++t) {
    int cur = t & 1;
    if (t + 1 < 8) stage(t + 1, cur ^ 1);
    compute(cur);
    __syncthreads();
  }

  unsigned short* dst = XWT + bm * 8192;
#pragma unroll
  for (int mi = 0; mi < 2; ++mi)
#pragma unroll
    for (int ni = 0; ni < 2; ++ni) {
      f32x4 z = acc[mi][ni];
      int n = bn * 128 + w * 32 + ni * 16 + lr;
      int mloc = mi * 16 + lq * 4;
      ushort4 u;
      u.x = f2bf_bits(z[0]); u.y = f2bf_bits(z[1]);
      u.z = f2bf_bits(z[2]); u.w = f2bf_bits(z[3]);
      *(ushort4*)(dst + n * 32 + mloc) = u;
    }
}

// ---------------- gemm1: Z = A_hat @ XW; out = X + s*(relu(Z) - X) ------------------
// BM=32, BN=256 (full), BK=32, 256 threads = 4 waves (each 32m x 64n).
// grid 256 = 1 block/CU. A read exactly once. NBUF=3 ring, raw s_barrier +
// counted vmcnt(10): 2 iterations of loads stay in flight across barriers.
__global__ __launch_bounds__(256, 1) void gemm_main(
    const float* __restrict__ A,              // [8192][8192]
    const unsigned short* __restrict__ B,     // XWT tiled [256][256][32]
    const float* __restrict__ X,              // [8192][256]
    const float* __restrict__ s,              // [8192]
    float* __restrict__ out) {                // [8192][256]
  __shared__ float As[3][32 * 32];            // 12 KB (XOR-swizzled 16B slots)
  __shared__ unsigned short Bs[3][256 * 32];  // 48 KB (linear, [n][32k])

  const int m0 = blockIdx.x * 32;
  const int tid = threadIdx.x;
  const int w = tid >> 6;
  const int l = tid & 63;
  const int lr = l & 15;
  const int lq = l >> 4;

  // A staging: lane writes LDS byte tid*16 (HW: wave base + l*16).
  // LDS promise: row r, 16B slot q holds global k-slot (q ^ (r&7)).
  const int rA = tid >> 3;
  const int qA = tid & 7;
  const int sA = qA ^ (rA & 7);
  const char* Asrc = (const char*)A + (size_t)(m0 + rA) * 32768 + sA * 16;
  const char* Bsrc = (const char*)B + tid * 16;

  f32x4 acc[2][4];
#pragma unroll
  for (int i = 0; i < 2; ++i)
#pragma unroll
    for (int j = 0; j < 4; ++j) acc[i][j] = (f32x4){0.f, 0.f, 0.f, 0.f};

  auto stage = [&](int t, int buf) {
    gload16_nt(Asrc + (size_t)t * 128, (char*)&As[buf][0] + w * 1024);
    const char* bs = Bsrc + (size_t)t * 16384;
    char* bd = (char*)&Bs[buf][0] + w * 1024;
#pragma unroll
    for (int j = 0; j < 4; ++j) gload16(bs + j * 4096, bd + j * 4096);
  };

  auto compute = [&](int buf) {
    bf16x8 af[2];
#pragma unroll
    for (int mi = 0; mi < 2; ++mi) {
      int r = mi * 16 + lr;
      const char* ap = (const char*)&As[buf][0] + r * 128;
      int s0 = (2 * lq) ^ (r & 7);
      int s1 = (2 * lq + 1) ^ (r & 7);
      f32x4 a0 = *(const f32x4*)(ap + s0 * 16);
      f32x4 a1 = *(const f32x4*)(ap + s1 * 16);
      bf16x8 v;
      v[0] = (__bf16)a0.x; v[1] = (__bf16)a0.y; v[2] = (__bf16)a0.z; v[3] = (__bf16)a0.w;
      v[4] = (__bf16)a1.x; v[5] = (__bf16)a1.y; v[6] = (__bf16)a1.z; v[7] = (__bf16)a1.w;
      af[mi] = v;
    }
    bf16x8 bfr[4];
#pragma unroll
    for (int ni = 0; ni < 4; ++ni) {
      int n = w * 64 + ni * 16 + lr;
      bfr[ni] = *(const bf16x8*)((const char*)&Bs[buf][0] + n * 64 + lq * 16);
    }
#pragma unroll
    for (int mi = 0; mi < 2; ++mi)
#pragma unroll
      for (int ni = 0; ni < 4; ++ni)
        acc[mi][ni] = __builtin_amdgcn_mfma_f32_16x16x32_bf16(af[mi], bfr[ni], acc[mi][ni], 0, 0, 0);
  };

  // prologue: buffers 0,1 in flight
  stage(0, 0);
  stage(1, 1);

  int bc = 0;  // compute buffer = t % 3
  for (int t = 0; t < 254; ++t) {
    int b2 = (bc + 2 >= 3) ? bc - 1 : bc + 2;  // (t+2) % 3
    stage(t + 2, b2);
    // wait: my 5 loads for buffer bc (oldest) done; 10 newer stay in flight
    asm volatile("s_waitcnt vmcnt(10)" ::: "memory");
    asm volatile("s_barrier" ::: "memory");  // all waves' buf-t data landed
    compute(bc);
    // reads complete before anyone overwrites buf bc next iteration
    asm volatile("s_waitcnt lgkmcnt(0)" ::: "memory");
    asm volatile("s_barrier" ::: "memory");
    bc = (bc + 1 >= 3) ? 0 : bc + 1;
  }
  // t = 254 (no stage)
  asm volatile("s_waitcnt vmcnt(5)" ::: "memory");
  asm volatile("s_barrier" ::: "memory");
  compute(bc);
  asm volatile("s_waitcnt lgkmcnt(0)" ::: "memory");
  asm volatile("s_barrier" ::: "memory");
  bc = (bc + 1 >= 3) ? 0 : bc + 1;
  // t = 255
  asm volatile("s_waitcnt vmcnt(0)" ::: "memory");
  asm volatile("s_barrier" ::: "memory");
  compute(bc);

  // fused epilogue: out = x + s*(relu(z) - x)
#pragma unroll
  for (int mi = 0; mi < 2; ++mi)
#pragma unroll
    for (int ni = 0; ni < 4; ++ni) {
      f32x4 z = acc[mi][ni];
      int n = w * 64 + ni * 16 + lr;
#pragma unroll
      for (int i = 0; i < 4; ++i) {
        int m = m0 + mi * 16 + lq * 4 + i;
        float x = X[m * 256 + n];
        float sv = s[m];
        out[m * 256 + n] = x + sv * (fmaxf(z[i], 0.f) - x);
      }
    }
}

extern "C" void kernel_launch(void* const* d_in, const int* in_sizes, int n_in,
                              void* d_out, int out_size, void* d_ws, size_t ws_size,
                              hipStream_t stream) {
  const float* X = (const float*)d_in[0];
  const float* A = (const float*)d_in[1];
  const float* wg = (const float*)d_in[2];
  const float* wl = (const float*)d_in[3];
  const float* W = (const float*)d_in[4];
  float* out = (float*)d_out;

  // ws: XWT tiled bf16 [256][256][32] = 4 MiB, WT bf16 128 KiB, s f32 32 KiB
  unsigned short* XWT = (unsigned short*)d_ws;
  unsigned short* WT = (unsigned short*)((char*)d_ws + 4194304);
  float* s = (float*)((char*)d_ws + 4194304 + 131072);

  prep_kernel<<<256, 256, 0, stream>>>(W, wg, wl, WT, s);
  gemm_xw<<<512, 256, 0, stream>>>(X, WT, XWT);
  gemm_main<<<256, 256, 0, stream>>>(A, XWT, X, s, out);
}

// Round 3
// 180.975 us; speedup vs baseline: 1.4562x; 1.4562x over previous
//
#include <hip/hip_runtime.h>
#include <hip/hip_bf16.h>

// out = X + s*(relu(A_hat @ (X @ W_agg)) - X), s = sigmoid(wg)*sigmoid(wl)
// X[8192,256] f32, A_hat[8192,8192] f32, W[256,256] f32. Out f32 [8192,256].
// Roofline: A (268MB, read once) => ~43us floor. Round-2 lesson: B (XWT, 4MB)
// re-read 256x = 1GB was the real wall (L2-thrashed by A). This round: A loads
// use CPol NT|SC1 (bypass L2) so B stays L2-resident; BK=64; NBUF=3 ring with
// counted vmcnt so ~80KB/CU stays in flight.

typedef __attribute__((ext_vector_type(4))) float f32x4;
typedef __attribute__((ext_vector_type(8))) __bf16 bf16x8;

#define GLOBAL_AS __attribute__((address_space(1)))
#define LDS_AS __attribute__((address_space(3)))

static __device__ __forceinline__ void gload16(const void* g, void* l) {
  __builtin_amdgcn_global_load_lds((const GLOBAL_AS void*)g, (LDS_AS void*)l, 16, 0, 0);
}
// A stream: NT(bit1) | SC1(bit4) = 0x12 -> non-temporal, L2-bypass scope.
// Goal: keep the 4MB B tile L2-resident instead of being churned out by A.
static __device__ __forceinline__ void gload16_stream(const void* g, void* l) {
  __builtin_amdgcn_global_load_lds((const GLOBAL_AS void*)g, (LDS_AS void*)l, 16, 0, 0x12);
}

static __device__ __forceinline__ unsigned short f2bf_bits(float f) {
  __bf16 h = (__bf16)f;
  return __builtin_bit_cast(unsigned short, h);
}

// ---------------- prep: s vector + W^T (bf16, tiled [k/32][n=256][32]) -------------
__global__ void prep_kernel(const float* __restrict__ W,
                            const float* __restrict__ wg,
                            const float* __restrict__ wl,
                            unsigned short* __restrict__ WT,  // [8][256][32] bf16
                            float* __restrict__ s) {
  int tid = blockIdx.x * 256 + threadIdx.x;  // 0..65535
  int k = tid >> 8, n = tid & 255;
  float w = W[tid];  // W[k][n]
  int kt = k >> 5, kloc = k & 31;
  WT[kt * 8192 + n * 32 + kloc] = f2bf_bits(w);
  if (tid < 8192) {
    float sg = 1.0f / (1.0f + expf(-wg[0]));
    float sl = 1.0f / (1.0f + expf(-wl[tid]));
    s[tid] = sg * sl;
  }
}

// ---------------- gemm0: XW = X @ W, write XW^T bf16 tiled [k/32][n=256][32] -------
__global__ __launch_bounds__(256, 2) void gemm_xw(
    const float* __restrict__ X,              // [8192][256]
    const unsigned short* __restrict__ WT,    // tiled [8][256][32]
    unsigned short* __restrict__ XWT) {       // tiled [256][256][32]
  __shared__ float As[2][32 * 32];
  __shared__ unsigned short Bs[2][128 * 32];

  const int bm = blockIdx.x & 255;
  const int bn = blockIdx.x >> 8;
  const int m0 = bm * 32;
  const int tid = threadIdx.x;
  const int w = tid >> 6;
  const int l = tid & 63;
  const int lr = l & 15;
  const int lq = l >> 4;

  const int pA = w * 1024 + l * 16;
  const int rA = pA >> 7;
  const int qA = (pA >> 4) & 7;
  const int ssA = qA ^ (rA & 7);
  const char* Asrc0 = (const char*)X + (size_t)(m0 + rA) * 1024 + ssA * 16;
  const char* Bsrc0 = (const char*)WT + bn * 8192 + w * 2048 + l * 16;

  f32x4 acc[2][2];
#pragma unroll
  for (int i = 0; i < 2; ++i)
#pragma unroll
    for (int j = 0; j < 2; ++j) acc[i][j] = (f32x4){0.f, 0.f, 0.f, 0.f};

  auto stage = [&](int t, int buf) {
    gload16(Asrc0 + (size_t)t * 128, (char*)&As[buf][0] + w * 1024);
    const char* bs = Bsrc0 + (size_t)t * 16384;
    gload16(bs, (char*)&Bs[buf][0] + w * 2048);
    gload16(bs + 1024, (char*)&Bs[buf][0] + w * 2048 + 1024);
  };

  auto compute = [&](int buf) {
    bf16x8 af[2];
#pragma unroll
    for (int mi = 0; mi < 2; ++mi) {
      int r = mi * 16 + lr;
      const float* ap = &As[buf][r * 32];
      int s0 = (2 * lq) ^ (r & 7);
      int s1 = (2 * lq + 1) ^ (r & 7);
      f32x4 a0 = *(const f32x4*)(ap + s0 * 4);
      f32x4 a1 = *(const f32x4*)(ap + s1 * 4);
      bf16x8 v;
      v[0] = (__bf16)a0.x; v[1] = (__bf16)a0.y; v[2] = (__bf16)a0.z; v[3] = (__bf16)a0.w;
      v[4] = (__bf16)a1.x; v[5] = (__bf16)a1.y; v[6] = (__bf16)a1.z; v[7] = (__bf16)a1.w;
      af[mi] = v;
    }
    bf16x8 bfr[2];
#pragma unroll
    for (int ni = 0; ni < 2; ++ni) {
      int row = w * 32 + ni * 16 + lr;
      bfr[ni] = *(const bf16x8*)(&Bs[buf][row * 32 + lq * 8]);
    }
#pragma unroll
    for (int mi = 0; mi < 2; ++mi)
#pragma unroll
      for (int ni = 0; ni < 2; ++ni)
        acc[mi][ni] = __builtin_amdgcn_mfma_f32_16x16x32_bf16(af[mi], bfr[ni], acc[mi][ni], 0, 0, 0);
  };

  stage(0, 0);
  __syncthreads();
  for (int t = 0; t < 8; ++t) {
    int cur = t & 1;
    if (t + 1 < 8) stage(t + 1, cur ^ 1);
    compute(cur);
    __syncthreads();
  }

  unsigned short* dst = XWT + bm * 8192;
#pragma unroll
  for (int mi = 0; mi < 2; ++mi)
#pragma unroll
    for (int ni = 0; ni < 2; ++ni) {
      f32x4 z = acc[mi][ni];
      int n = bn * 128 + w * 32 + ni * 16 + lr;
      int mloc = mi * 16 + lq * 4;
      ushort4 u;
      u.x = f2bf_bits(z[0]); u.y = f2bf_bits(z[1]);
      u.z = f2bf_bits(z[2]); u.w = f2bf_bits(z[3]);
      *(ushort4*)(dst + n * 32 + mloc) = u;
    }
}

// ---------------- gemm1: Z = A_hat @ XW; out = X + s*(relu(Z) - X) ------------------
// BM=32, BN=256, BK=64, 256 threads = 4 waves (each 32m x 64n), grid 256.
// A read exactly once, streamed around L2 (NT|SC1). B re-reads hit L2.
// NBUF=3 ring, raw s_barrier + vmcnt(20): 2 iters x 10 loads stay in flight.
__global__ __launch_bounds__(256, 1) void gemm_main(
    const float* __restrict__ A,              // [8192][8192]
    const unsigned short* __restrict__ B,     // XWT tiled [256][256][32]
    const float* __restrict__ X,              // [8192][256]
    const float* __restrict__ s,              // [8192]
    float* __restrict__ out) {                // [8192][256]
  __shared__ float As[3][32 * 64];            // 3 x 8KB, 16-slot XOR swizzle per row
  __shared__ unsigned short Bs[3][2 * 256 * 32];  // 3 x 32KB, two kt-tiles [n][32]

  const int m0 = blockIdx.x * 32;
  const int tid = threadIdx.x;
  const int w = tid >> 6;
  const int l = tid & 63;
  const int lr = l & 15;
  const int lq = l >> 4;

  // A staging (2 instructions/wave/iter): instr j dest byte p = w*2048 + j*1024 + l*16.
  // LDS promise: row r (256B), slot q holds global k-slot (q ^ (r&15)).
  auto mkAsrc = [&](int p) {
    int r = p >> 8;
    int q = (p >> 4) & 15;
    int sq = q ^ (r & 15);
    return (const char*)A + (size_t)(m0 + r) * 32768 + sq * 16;
  };
  const char* AsrcJ0 = mkAsrc(w * 2048 + l * 16);
  const char* AsrcJ1 = mkAsrc(w * 2048 + 1024 + l * 16);
  const char* Bsrc = (const char*)B + w * 8192 + l * 16;

  f32x4 acc[2][4];
#pragma unroll
  for (int i = 0; i < 2; ++i)
#pragma unroll
    for (int j = 0; j < 4; ++j) acc[i][j] = (f32x4){0.f, 0.f, 0.f, 0.f};

  auto stage = [&](int t, int buf) {
    char* Ad = (char*)&As[buf][0] + w * 2048;
    gload16_stream(AsrcJ0 + (size_t)t * 256, Ad);
    gload16_stream(AsrcJ1 + (size_t)t * 256, Ad + 1024);
    const char* bs = Bsrc + (size_t)t * 32768;
    char* bd = (char*)&Bs[buf][0] + w * 8192;
#pragma unroll
    for (int j = 0; j < 8; ++j) gload16(bs + j * 1024, bd + j * 1024);
  };

  auto compute = [&](int buf) {
    const char* Ab = (const char*)&As[buf][0];
    const char* Bb = (const char*)&Bs[buf][0];
    bf16x8 af[2][2];  // [kk][mi]
#pragma unroll
    for (int kk = 0; kk < 2; ++kk)
#pragma unroll
      for (int mi = 0; mi < 2; ++mi) {
        int r = mi * 16 + lr;
        int s0 = (kk * 8 + 2 * lq) ^ (r & 15);
        int s1 = (kk * 8 + 2 * lq + 1) ^ (r & 15);
        f32x4 a0 = *(const f32x4*)(Ab + r * 256 + s0 * 16);
        f32x4 a1 = *(const f32x4*)(Ab + r * 256 + s1 * 16);
        bf16x8 v;
        v[0] = (__bf16)a0.x; v[1] = (__bf16)a0.y; v[2] = (__bf16)a0.z; v[3] = (__bf16)a0.w;
        v[4] = (__bf16)a1.x; v[5] = (__bf16)a1.y; v[6] = (__bf16)a1.z; v[7] = (__bf16)a1.w;
        af[kk][mi] = v;
      }
    bf16x8 bfr[2][4];  // [kk][ni]
#pragma unroll
    for (int kk = 0; kk < 2; ++kk)
#pragma unroll
      for (int ni = 0; ni < 4; ++ni) {
        int n = w * 64 + ni * 16 + lr;
        bfr[kk][ni] = *(const bf16x8*)(Bb + kk * 16384 + n * 64 + lq * 16);
      }
#pragma unroll
    for (int kk = 0; kk < 2; ++kk)
#pragma unroll
      for (int mi = 0; mi < 2; ++mi)
#pragma unroll
        for (int ni = 0; ni < 4; ++ni)
          acc[mi][ni] =
              __builtin_amdgcn_mfma_f32_16x16x32_bf16(af[kk][mi], bfr[kk][ni], acc[mi][ni], 0, 0, 0);
  };

  // prologue: buffers 0,1 in flight
  stage(0, 0);
  stage(1, 1);

  int bc = 0;  // compute buffer = t % 3
  for (int t = 0; t < 126; ++t) {
    int b2 = (bc + 2 >= 3) ? bc - 1 : bc + 2;  // (t+2) % 3
    stage(t + 2, b2);
    // buf bc's 10 loads (oldest) done; 20 newer stay in flight
    asm volatile("s_waitcnt vmcnt(20)" ::: "memory");
    asm volatile("s_barrier" ::: "memory");
    compute(bc);
    asm volatile("s_waitcnt lgkmcnt(0)" ::: "memory");
    asm volatile("s_barrier" ::: "memory");
    bc = (bc + 1 >= 3) ? 0 : bc + 1;
  }
  // t = 126 (no stage)
  asm volatile("s_waitcnt vmcnt(10)" ::: "memory");
  asm volatile("s_barrier" ::: "memory");
  compute(bc);
  asm volatile("s_waitcnt lgkmcnt(0)" ::: "memory");
  asm volatile("s_barrier" ::: "memory");
  bc = (bc + 1 >= 3) ? 0 : bc + 1;
  // t = 127
  asm volatile("s_waitcnt vmcnt(0)" ::: "memory");
  asm volatile("s_barrier" ::: "memory");
  compute(bc);

  // fused epilogue: out = x + s*(relu(z) - x)
#pragma unroll
  for (int mi = 0; mi < 2; ++mi)
#pragma unroll
    for (int ni = 0; ni < 4; ++ni) {
      f32x4 z = acc[mi][ni];
      int n = w * 64 + ni * 16 + lr;
#pragma unroll
      for (int i = 0; i < 4; ++i) {
        int m = m0 + mi * 16 + lq * 4 + i;
        float x = X[m * 256 + n];
        float sv = s[m];
        out[m * 256 + n] = x + sv * (fmaxf(z[i], 0.f) - x);
      }
    }
}

extern "C" void kernel_launch(void* const* d_in, const int* in_sizes, int n_in,
                              void* d_out, int out_size, void* d_ws, size_t ws_size,
                              hipStream_t stream) {
  const float* X = (const float*)d_in[0];
  const float* A = (const float*)d_in[1];
  const float* wg = (const float*)d_in[2];
  const float* wl = (const float*)d_in[3];
  const float* W = (const float*)d_in[4];
  float* out = (float*)d_out;

  // ws: XWT tiled bf16 [256][256][32] = 4 MiB, WT bf16 128 KiB, s f32 32 KiB
  unsigned short* XWT = (unsigned short*)d_ws;
  unsigned short* WT = (unsigned short*)((char*)d_ws + 4194304);
  float* s = (float*)((char*)d_ws + 4194304 + 131072);

  prep_kernel<<<256, 256, 0, stream>>>(W, wg, wl, WT, s);
  gemm_xw<<<512, 256, 0, stream>>>(X, WT, XWT);
  gemm_main<<<256, 256, 0, stream>>>(A, XWT, X, s, out);
}

// Round 4
// 161.407 us; speedup vs baseline: 1.6327x; 1.1212x over previous
//
#include <hip/hip_runtime.h>
#include <hip/hip_bf16.h>

// out = X + s*(relu(A_hat @ (X @ W_agg)) - X), s = sigmoid(wg)*sigmoid(wl)
// X[8192,256] f32, A_hat[8192,8192] f32, W[256,256] f32. Out f32 [8192,256].
// A (268MB) read once (BN=256): HBM floor ~43us. B (XWT 4MB, L2-resident)
// re-read 256x = 1GB L2 traffic. Round-4: 8 waves/block (512 thr) so each wave
// issues only 5 loads/iter and waves overlap each other's stalls; XWT global
// layout pre-swizzled (16B slot ^= f(n)) to kill the 4-way B-read bank conflict.

typedef __attribute__((ext_vector_type(4))) float f32x4;
typedef __attribute__((ext_vector_type(8))) __bf16 bf16x8;

#define GLOBAL_AS __attribute__((address_space(1)))
#define LDS_AS __attribute__((address_space(3)))

static __device__ __forceinline__ void gload16(const void* g, void* l) {
  __builtin_amdgcn_global_load_lds((const GLOBAL_AS void*)g, (LDS_AS void*)l, 16, 0, 0);
}
// A stream: NT(bit1)|SC1(bit4) -> keep B/X/out resident in L2.
static __device__ __forceinline__ void gload16_stream(const void* g, void* l) {
  __builtin_amdgcn_global_load_lds((const GLOBAL_AS void*)g, (LDS_AS void*)l, 16, 0, 0x12);
}

static __device__ __forceinline__ unsigned short f2bf_bits(float f) {
  __bf16 h = (__bf16)f;
  return __builtin_bit_cast(unsigned short, h);
}

// ---------------- prep: s vector + W^T (bf16, tiled [k/32][n=256][32]) -------------
__global__ void prep_kernel(const float* __restrict__ W,
                            const float* __restrict__ wg,
                            const float* __restrict__ wl,
                            unsigned short* __restrict__ WT,  // [8][256][32] bf16
                            float* __restrict__ s) {
  int tid = blockIdx.x * 256 + threadIdx.x;  // 0..65535
  int k = tid >> 8, n = tid & 255;
  float w = W[tid];  // W[k][n]
  int kt = k >> 5, kloc = k & 31;
  WT[kt * 8192 + n * 32 + kloc] = f2bf_bits(w);
  if (tid < 8192) {
    float sg = 1.0f / (1.0f + expf(-wg[0]));
    float sl = 1.0f / (1.0f + expf(-wl[tid]));
    s[tid] = sg * sl;
  }
}

// ---------------- gemm0: XW = X @ W, write XW^T bf16 tiled [k/32][n=256][32] -------
// XWT rows are 32 elems = four 16B slots; slot position swizzled: q' = q ^ (((n>>2)^n)&3)
__global__ __launch_bounds__(256, 2) void gemm_xw(
    const float* __restrict__ X,              // [8192][256]
    const unsigned short* __restrict__ WT,    // tiled [8][256][32]
    unsigned short* __restrict__ XWT) {       // tiled [256][256][32], slot-swizzled
  __shared__ float As[2][32 * 32];
  __shared__ unsigned short Bs[2][128 * 32];

  const int bm = blockIdx.x & 255;
  const int bn = blockIdx.x >> 8;
  const int m0 = bm * 32;
  const int tid = threadIdx.x;
  const int w = tid >> 6;
  const int l = tid & 63;
  const int lr = l & 15;
  const int lq = l >> 4;

  const int pA = w * 1024 + l * 16;
  const int rA = pA >> 7;
  const int qA = (pA >> 4) & 7;
  const int ssA = qA ^ (rA & 7);
  const char* Asrc0 = (const char*)X + (size_t)(m0 + rA) * 1024 + ssA * 16;
  const char* Bsrc0 = (const char*)WT + bn * 8192 + w * 2048 + l * 16;

  f32x4 acc[2][2];
#pragma unroll
  for (int i = 0; i < 2; ++i)
#pragma unroll
    for (int j = 0; j < 2; ++j) acc[i][j] = (f32x4){0.f, 0.f, 0.f, 0.f};

  auto stage = [&](int t, int buf) {
    gload16(Asrc0 + (size_t)t * 128, (char*)&As[buf][0] + w * 1024);
    const char* bs = Bsrc0 + (size_t)t * 16384;
    gload16(bs, (char*)&Bs[buf][0] + w * 2048);
    gload16(bs + 1024, (char*)&Bs[buf][0] + w * 2048 + 1024);
  };

  auto compute = [&](int buf) {
    bf16x8 af[2];
#pragma unroll
    for (int mi = 0; mi < 2; ++mi) {
      int r = mi * 16 + lr;
      const float* ap = &As[buf][r * 32];
      int s0 = (2 * lq) ^ (r & 7);
      int s1 = (2 * lq + 1) ^ (r & 7);
      f32x4 a0 = *(const f32x4*)(ap + s0 * 4);
      f32x4 a1 = *(const f32x4*)(ap + s1 * 4);
      bf16x8 v;
      v[0] = (__bf16)a0.x; v[1] = (__bf16)a0.y; v[2] = (__bf16)a0.z; v[3] = (__bf16)a0.w;
      v[4] = (__bf16)a1.x; v[5] = (__bf16)a1.y; v[6] = (__bf16)a1.z; v[7] = (__bf16)a1.w;
      af[mi] = v;
    }
    bf16x8 bfr[2];
#pragma unroll
    for (int ni = 0; ni < 2; ++ni) {
      int row = w * 32 + ni * 16 + lr;
      bfr[ni] = *(const bf16x8*)(&Bs[buf][row * 32 + lq * 8]);
    }
#pragma unroll
    for (int mi = 0; mi < 2; ++mi)
#pragma unroll
      for (int ni = 0; ni < 2; ++ni)
        acc[mi][ni] = __builtin_amdgcn_mfma_f32_16x16x32_bf16(af[mi], bfr[ni], acc[mi][ni], 0, 0, 0);
  };

  stage(0, 0);
  __syncthreads();
  for (int t = 0; t < 8; ++t) {
    int cur = t & 1;
    if (t + 1 < 8) stage(t + 1, cur ^ 1);
    compute(cur);
    __syncthreads();
  }

  unsigned short* dst = XWT + bm * 8192;
#pragma unroll
  for (int mi = 0; mi < 2; ++mi)
#pragma unroll
    for (int ni = 0; ni < 2; ++ni) {
      f32x4 z = acc[mi][ni];
      int n = bn * 128 + w * 32 + ni * 16 + lr;
      int q = mi * 2 + (lq >> 1);                 // 16B slot within the 64B row
      int qp = q ^ (((n >> 2) ^ n) & 3);          // swizzled slot
      ushort4 u;
      u.x = f2bf_bits(z[0]); u.y = f2bf_bits(z[1]);
      u.z = f2bf_bits(z[2]); u.w = f2bf_bits(z[3]);
      *(ushort4*)(dst + n * 32 + qp * 8 + (lq & 1) * 4) = u;
    }
}

// ---------------- gemm1: Z = A_hat @ XW; out = X + s*(relu(Z) - X) ------------------
// BM=32, BN=256, BK=64, 512 threads = 8 waves (each 32m x 32n), grid 256.
// NBUF=3 ring (120 KB LDS); 5 loads/wave/iter; vmcnt(10) = 2 iters in flight.
__global__ __launch_bounds__(512, 1) void gemm_main(
    const float* __restrict__ A,              // [8192][8192]
    const unsigned short* __restrict__ B,     // XWT tiled [256][256][32], slot-swizzled
    const float* __restrict__ X,              // [8192][256]
    const float* __restrict__ s,              // [8192]
    float* __restrict__ out) {                // [8192][256]
  __shared__ float As[3][32 * 64];                // 3 x 8 KB, 16-slot XOR swizzle
  __shared__ unsigned short Bs[3][2 * 256 * 32];  // 3 x 32 KB, kt-pair, slot-swizzled

  const int m0 = blockIdx.x * 32;
  const int tid = threadIdx.x;  // 0..511
  const int w = tid >> 6;       // 0..7
  const int l = tid & 63;
  const int lr = l & 15;
  const int lq = l >> 4;

  // A staging (1 instr/thread): thread t -> LDS byte t*16 (row r=t>>4, slot q=t&15).
  // LDS promise: row r slot q holds global k-slot q ^ (r&15).
  const int rA = tid >> 4;
  const int qA = tid & 15;
  const int sqA = qA ^ (rA & 15);
  const char* Asrc = (const char*)A + (size_t)(m0 + rA) * 32768 + sqA * 16;
  const char* Bsrc = (const char*)B + tid * 16;

  f32x4 acc[2][2];
#pragma unroll
  for (int i = 0; i < 2; ++i)
#pragma unroll
    for (int j = 0; j < 2; ++j) acc[i][j] = (f32x4){0.f, 0.f, 0.f, 0.f};

  auto stage = [&](int t, int buf) {
    gload16_stream(Asrc + (size_t)t * 256, (char*)&As[buf][0] + w * 1024);
    const char* bs = Bsrc + (size_t)t * 32768;
    char* bd = (char*)&Bs[buf][0] + w * 1024;
#pragma unroll
    for (int j = 0; j < 4; ++j) gload16(bs + j * 8192, bd + j * 8192);
  };

  auto compute = [&](int buf) {
    const char* Ab = (const char*)&As[buf][0];
    const char* Bb = (const char*)&Bs[buf][0];
    bf16x8 af[2][2];  // [kk][mi]
#pragma unroll
    for (int kk = 0; kk < 2; ++kk)
#pragma unroll
      for (int mi = 0; mi < 2; ++mi) {
        int r = mi * 16 + lr;
        int s0 = (kk * 8 + 2 * lq) ^ (r & 15);
        int s1 = s0 ^ 1;
        f32x4 a0 = *(const f32x4*)(Ab + r * 256 + s0 * 16);
        f32x4 a1 = *(const f32x4*)(Ab + r * 256 + s1 * 16);
        bf16x8 v;
        v[0] = (__bf16)a0.x; v[1] = (__bf16)a0.y; v[2] = (__bf16)a0.z; v[3] = (__bf16)a0.w;
        v[4] = (__bf16)a1.x; v[5] = (__bf16)a1.y; v[6] = (__bf16)a1.z; v[7] = (__bf16)a1.w;
        af[kk][mi] = v;
      }
    bf16x8 bfr[2][2];  // [kk][ni]
#pragma unroll
    for (int kk = 0; kk < 2; ++kk)
#pragma unroll
      for (int ni = 0; ni < 2; ++ni) {
        int n = w * 32 + ni * 16 + lr;
        int qp = lq ^ (((n >> 2) ^ n) & 3);  // un-swizzle the 16B slot
        bfr[kk][ni] = *(const bf16x8*)(Bb + kk * 16384 + n * 64 + qp * 16);
      }
#pragma unroll
    for (int kk = 0; kk < 2; ++kk)
#pragma unroll
      for (int mi = 0; mi < 2; ++mi)
#pragma unroll
        for (int ni = 0; ni < 2; ++ni)
          acc[mi][ni] =
              __builtin_amdgcn_mfma_f32_16x16x32_bf16(af[kk][mi], bfr[kk][ni], acc[mi][ni], 0, 0, 0);
  };

  // prologue: buffers 0,1 in flight (10 loads/wave outstanding)
  stage(0, 0);
  stage(1, 1);

  int bc = 0;  // compute buffer = t % 3
  for (int t = 0; t < 126; ++t) {
    int b2 = (bc + 2 >= 3) ? bc - 1 : bc + 2;  // (t+2) % 3
    stage(t + 2, b2);
    asm volatile("s_waitcnt vmcnt(10)" ::: "memory");  // buf bc's 5 loads landed
    asm volatile("s_barrier" ::: "memory");
    compute(bc);
    asm volatile("s_waitcnt lgkmcnt(0)" ::: "memory");  // my ds_reads done
    asm volatile("s_barrier" ::: "memory");             // before buf reuse
    bc = (bc + 1 >= 3) ? 0 : bc + 1;
  }
  // t = 126 (no stage)
  asm volatile("s_waitcnt vmcnt(5)" ::: "memory");
  asm volatile("s_barrier" ::: "memory");
  compute(bc);
  asm volatile("s_waitcnt lgkmcnt(0)" ::: "memory");
  asm volatile("s_barrier" ::: "memory");
  bc = (bc + 1 >= 3) ? 0 : bc + 1;
  // t = 127
  asm volatile("s_waitcnt vmcnt(0)" ::: "memory");
  asm volatile("s_barrier" ::: "memory");
  compute(bc);

  // fused epilogue: out = x + s*(relu(z) - x)
#pragma unroll
  for (int mi = 0; mi < 2; ++mi)
#pragma unroll
    for (int ni = 0; ni < 2; ++ni) {
      f32x4 z = acc[mi][ni];
      int n = w * 32 + ni * 16 + lr;
#pragma unroll
      for (int i = 0; i < 4; ++i) {
        int m = m0 + mi * 16 + lq * 4 + i;
        float x = X[m * 256 + n];
        float sv = s[m];
        out[m * 256 + n] = x + sv * (fmaxf(z[i], 0.f) - x);
      }
    }
}

extern "C" void kernel_launch(void* const* d_in, const int* in_sizes, int n_in,
                              void* d_out, int out_size, void* d_ws, size_t ws_size,
                              hipStream_t stream) {
  const float* X = (const float*)d_in[0];
  const float* A = (const float*)d_in[1];
  const float* wg = (const float*)d_in[2];
  const float* wl = (const float*)d_in[3];
  const float* W = (const float*)d_in[4];
  float* out = (float*)d_out;

  // ws: XWT tiled bf16 [256][256][32] = 4 MiB, WT bf16 128 KiB, s f32 32 KiB
  unsigned short* XWT = (unsigned short*)d_ws;
  unsigned short* WT = (unsigned short*)((char*)d_ws + 4194304);
  float* s = (float*)((char*)d_ws + 4194304 + 131072);

  prep_kernel<<<256, 256, 0, stream>>>(W, wg, wl, WT, s);
  gemm_xw<<<512, 256, 0, stream>>>(X, WT, XWT);
  gemm_main<<<256, 512, 0, stream>>>(A, XWT, X, s, out);
}

// Round 5
// 128.093 us; speedup vs baseline: 2.0573x; 1.2601x over previous
//
#include <hip/hip_runtime.h>
#include <hip/hip_bf16.h>

// out = X + s*(relu(A_hat @ (X @ W_agg)) - X), s = sigmoid(wg)*sigmoid(wl)
// X[8192,256] f32, A_hat[8192,8192] f32, W[256,256] f32. Out f32 [8192,256].
// Round 5: B fully out of LDS. gemm_xw writes XWT2 in MFMA-B-frag layout
// ([k16][w][kk,ni][lane][8bf16], 1KB coalesced blocks); gemm_main loads B-frags
// global->VGPR (L2-resident), LDS holds only A (4x8KB ring). Cuts per-iter LDS
// traffic 136KB -> 72KB (was the bottleneck: staged-B floor ~90us).

typedef __attribute__((ext_vector_type(4))) float f32x4;
typedef __attribute__((ext_vector_type(8))) __bf16 bf16x8;

#define GLOBAL_AS __attribute__((address_space(1)))
#define LDS_AS __attribute__((address_space(3)))

static __device__ __forceinline__ void gload16(const void* g, void* l) {
  __builtin_amdgcn_global_load_lds((const GLOBAL_AS void*)g, (LDS_AS void*)l, 16, 0, 0);
}
// A stream: NT(bit1)|SC1(bit4) -> protect L2 residency of B/X/out.
static __device__ __forceinline__ void gload16_stream(const void* g, void* l) {
  __builtin_amdgcn_global_load_lds((const GLOBAL_AS void*)g, (LDS_AS void*)l, 16, 0, 0x12);
}

static __device__ __forceinline__ unsigned short f2bf_bits(float f) {
  __bf16 h = (__bf16)f;
  return __builtin_bit_cast(unsigned short, h);
}

// ---------------- prep: s vector + W^T (bf16, tiled [k/32][n=256][32]) -------------
__global__ void prep_kernel(const float* __restrict__ W,
                            const float* __restrict__ wg,
                            const float* __restrict__ wl,
                            unsigned short* __restrict__ WT,  // [8][256][32] bf16
                            float* __restrict__ s) {
  int tid = blockIdx.x * 256 + threadIdx.x;  // 0..65535
  int k = tid >> 8, n = tid & 255;
  float w = W[tid];  // W[k][n]
  int kt = k >> 5, kloc = k & 31;
  WT[kt * 8192 + n * 32 + kloc] = f2bf_bits(w);
  if (tid < 8192) {
    float sg = 1.0f / (1.0f + expf(-wg[0]));
    float sl = 1.0f / (1.0f + expf(-wl[tid]));
    s[tid] = sg * sl;
  }
}

// ---------------- gemm0: XW = X @ W  ->  XWT2 in MFMA B-frag layout ----------------
// XWT2 block for (c=k/64, w=n/32, kk=(k>>5)&1, ni=(n>>4)&1): 64 lanes x 16B, where
// lane = (n&15) + 16*((k>>3)&3), holding 8 consecutive bf16 along k.
__global__ __launch_bounds__(256, 2) void gemm_xw(
    const float* __restrict__ X,              // [8192][256]
    const unsigned short* __restrict__ WT,    // tiled [8][256][32]
    unsigned short* __restrict__ XWT2) {      // 4 MiB, frag-layout
  __shared__ float As[2][32 * 32];
  __shared__ unsigned short Bs[2][128 * 32];

  const int bm = blockIdx.x & 255;
  const int bn = blockIdx.x >> 8;
  const int m0 = bm * 32;
  const int tid = threadIdx.x;
  const int w = tid >> 6;
  const int l = tid & 63;
  const int lr = l & 15;
  const int lq = l >> 4;

  const int pA = w * 1024 + l * 16;
  const int rA = pA >> 7;
  const int qA = (pA >> 4) & 7;
  const int ssA = qA ^ (rA & 7);
  const char* Asrc0 = (const char*)X + (size_t)(m0 + rA) * 1024 + ssA * 16;
  const char* Bsrc0 = (const char*)WT + bn * 8192 + w * 2048 + l * 16;

  f32x4 acc[2][2];
#pragma unroll
  for (int i = 0; i < 2; ++i)
#pragma unroll
    for (int j = 0; j < 2; ++j) acc[i][j] = (f32x4){0.f, 0.f, 0.f, 0.f};

  auto stage = [&](int t, int buf) {
    gload16(Asrc0 + (size_t)t * 128, (char*)&As[buf][0] + w * 1024);
    const char* bs = Bsrc0 + (size_t)t * 16384;
    gload16(bs, (char*)&Bs[buf][0] + w * 2048);
    gload16(bs + 1024, (char*)&Bs[buf][0] + w * 2048 + 1024);
  };

  auto compute = [&](int buf) {
    bf16x8 af[2];
#pragma unroll
    for (int mi = 0; mi < 2; ++mi) {
      int r = mi * 16 + lr;
      const float* ap = &As[buf][r * 32];
      int s0 = (2 * lq) ^ (r & 7);
      int s1 = (2 * lq + 1) ^ (r & 7);
      f32x4 a0 = *(const f32x4*)(ap + s0 * 4);
      f32x4 a1 = *(const f32x4*)(ap + s1 * 4);
      bf16x8 v;
      v[0] = (__bf16)a0.x; v[1] = (__bf16)a0.y; v[2] = (__bf16)a0.z; v[3] = (__bf16)a0.w;
      v[4] = (__bf16)a1.x; v[5] = (__bf16)a1.y; v[6] = (__bf16)a1.z; v[7] = (__bf16)a1.w;
      af[mi] = v;
    }
    bf16x8 bfr[2];
#pragma unroll
    for (int ni = 0; ni < 2; ++ni) {
      int row = w * 32 + ni * 16 + lr;
      bfr[ni] = *(const bf16x8*)(&Bs[buf][row * 32 + lq * 8]);
    }
#pragma unroll
    for (int mi = 0; mi < 2; ++mi)
#pragma unroll
      for (int ni = 0; ni < 2; ++ni)
        acc[mi][ni] = __builtin_amdgcn_mfma_f32_16x16x32_bf16(af[mi], bfr[ni], acc[mi][ni], 0, 0, 0);
  };

  stage(0, 0);
  __syncthreads();
  for (int t = 0; t < 8; ++t) {
    int cur = t & 1;
    if (t + 1 < 8) stage(t + 1, cur ^ 1);
    compute(cur);
    __syncthreads();
  }

  // epilogue -> XWT2 frag layout. k (main-GEMM) = bm*32 + mi*16 + lq*4 + i
#pragma unroll
  for (int mi = 0; mi < 2; ++mi)
#pragma unroll
    for (int ni2 = 0; ni2 < 2; ++ni2) {
      f32x4 z = acc[mi][ni2];
      int n = bn * 128 + w * 32 + ni2 * 16 + lr;
      int k = bm * 32 + mi * 16 + lq * 4;
      int c = k >> 6;
      int kk = (k >> 5) & 1;
      int ni = (n >> 4) & 1;
      int wp = n >> 5;
      int lane2 = (n & 15) + 16 * ((k >> 3) & 3);
      int j0 = k & 7;  // 0 or 4
      size_t off = (((size_t)c * 8 + wp) * 4 + kk * 2 + ni) * 512 + lane2 * 8 + j0;
      ushort4 u;
      u.x = f2bf_bits(z[0]); u.y = f2bf_bits(z[1]);
      u.z = f2bf_bits(z[2]); u.w = f2bf_bits(z[3]);
      *(ushort4*)(XWT2 + off) = u;
    }
}

// ---------------- gemm1: Z = A_hat @ XW; out = X + s*(relu(Z) - X) ------------------
// BM=32, BN=256, BK=64, 512 threads = 8 waves (wave w: 32m x 32n at n0=w*32).
// LDS: A only, 4-buffer ring (32 KB). B-frags direct global->VGPR from XWT2 (L2),
// double-buffered in two named reg sets, 1-iter prefetch. vmcnt(6) steady state.
__global__ __launch_bounds__(512, 1) void gemm_main(
    const float* __restrict__ A,              // [8192][8192]
    const unsigned short* __restrict__ B2,    // XWT2 frag layout
    const float* __restrict__ X,              // [8192][256]
    const float* __restrict__ s,              // [8192]
    float* __restrict__ out) {                // [8192][256]
  __shared__ float As[4][32 * 64];  // 4 x 8 KB ring, rows 256B, 16-slot XOR swizzle

  const int m0 = blockIdx.x * 32;
  const int tid = threadIdx.x;  // 0..511
  const int w = tid >> 6;       // 0..7
  const int l = tid & 63;
  const int lr = l & 15;
  const int lq = l >> 4;

  // A staging: thread t -> LDS byte t*16 (row r=t>>4, slot q=t&15).
  // LDS promise: row r slot q holds global k-slot q ^ (r&15).
  const int rA = tid >> 4;
  const int qA = tid & 15;
  const int sqA = qA ^ (rA & 15);
  const char* Asrc = (const char*)A + (size_t)(m0 + rA) * 32768 + sqA * 16;
  const char* Bbase = (const char*)B2 + (size_t)w * 4096 + (size_t)l * 16;

  f32x4 acc[2][2];
#pragma unroll
  for (int i = 0; i < 2; ++i)
#pragma unroll
    for (int j = 0; j < 2; ++j) acc[i][j] = (f32x4){0.f, 0.f, 0.f, 0.f};

  struct BF { bf16x8 a, b, c, d; };  // (kk,ni) = (0,0),(0,1),(1,0),(1,1)
  BF Bf0, Bf1;

  auto stageA = [&](int h, int buf) {
    gload16_stream(Asrc + (size_t)h * 256, (char*)&As[buf][0] + w * 1024);
  };
  auto loadB = [&](int h, BF& f) {
    const char* p = Bbase + (size_t)h * 32768;
    f.a = *(const bf16x8*)(p);
    f.b = *(const bf16x8*)(p + 1024);
    f.c = *(const bf16x8*)(p + 2048);
    f.d = *(const bf16x8*)(p + 3072);
  };

  auto compute = [&](int buf, const BF& f) {
    const char* Ab = (const char*)&As[buf][0];
    bf16x8 af[2][2];  // [kk][mi]
#pragma unroll
    for (int kk = 0; kk < 2; ++kk)
#pragma unroll
      for (int mi = 0; mi < 2; ++mi) {
        int r = mi * 16 + lr;
        int s0 = (kk * 8 + 2 * lq) ^ (r & 15);
        int s1 = ((kk * 8 + 2 * lq) + 1) ^ (r & 15);
        f32x4 a0 = *(const f32x4*)(Ab + r * 256 + s0 * 16);
        f32x4 a1 = *(const f32x4*)(Ab + r * 256 + s1 * 16);
        bf16x8 v;
        v[0] = (__bf16)a0.x; v[1] = (__bf16)a0.y; v[2] = (__bf16)a0.z; v[3] = (__bf16)a0.w;
        v[4] = (__bf16)a1.x; v[5] = (__bf16)a1.y; v[6] = (__bf16)a1.z; v[7] = (__bf16)a1.w;
        af[kk][mi] = v;
      }
    acc[0][0] = __builtin_amdgcn_mfma_f32_16x16x32_bf16(af[0][0], f.a, acc[0][0], 0, 0, 0);
    acc[0][1] = __builtin_amdgcn_mfma_f32_16x16x32_bf16(af[0][0], f.b, acc[0][1], 0, 0, 0);
    acc[1][0] = __builtin_amdgcn_mfma_f32_16x16x32_bf16(af[0][1], f.a, acc[1][0], 0, 0, 0);
    acc[1][1] = __builtin_amdgcn_mfma_f32_16x16x32_bf16(af[0][1], f.b, acc[1][1], 0, 0, 0);
    acc[0][0] = __builtin_amdgcn_mfma_f32_16x16x32_bf16(af[1][0], f.c, acc[0][0], 0, 0, 0);
    acc[0][1] = __builtin_amdgcn_mfma_f32_16x16x32_bf16(af[1][0], f.d, acc[0][1], 0, 0, 0);
    acc[1][0] = __builtin_amdgcn_mfma_f32_16x16x32_bf16(af[1][1], f.c, acc[1][0], 0, 0, 0);
    acc[1][1] = __builtin_amdgcn_mfma_f32_16x16x32_bf16(af[1][1], f.d, acc[1][1], 0, 0, 0);
  };

  // prologue (FIFO order matters for vmcnt math): A0, B0x4, A1, B1x4, A2, A3
  stageA(0, 0);
  loadB(0, Bf0);
  stageA(1, 1);
  loadB(1, Bf1);
  stageA(2, 2);
  stageA(3, 3);

  // steady state: entering half-iter h, FIFO = [B(h)x4, A(h+2), B(h+1)x4, A(h+3)];
  // vmcnt(6) forces B(h) (and older) done; A(h) was forced long ago.
  for (int h = 0; h < 124; h += 2) {
    asm volatile("s_waitcnt vmcnt(6)" ::: "memory");
    asm volatile("s_barrier" ::: "memory");
    compute(h & 3, Bf0);
    asm volatile("s_waitcnt lgkmcnt(0)" ::: "memory");
    asm volatile("s_barrier" ::: "memory");
    loadB(h + 2, Bf0);
    stageA(h + 4, h & 3);

    asm volatile("s_waitcnt vmcnt(6)" ::: "memory");
    asm volatile("s_barrier" ::: "memory");
    compute((h + 1) & 3, Bf1);
    asm volatile("s_waitcnt lgkmcnt(0)" ::: "memory");
    asm volatile("s_barrier" ::: "memory");
    loadB(h + 3, Bf1);
    stageA(h + 5, (h + 1) & 3);
  }
  // tail: h = 124..127 (last loop iter h=122 issued B(124),B(125),A(126),A(127))
  asm volatile("s_waitcnt vmcnt(6)" ::: "memory");
  asm volatile("s_barrier" ::: "memory");
  compute(0, Bf0);  // 124
  asm volatile("s_waitcnt lgkmcnt(0)" ::: "memory");
  asm volatile("s_barrier" ::: "memory");
  loadB(126, Bf0);

  asm volatile("s_waitcnt vmcnt(5)" ::: "memory");
  asm volatile("s_barrier" ::: "memory");
  compute(1, Bf1);  // 125
  asm volatile("s_waitcnt lgkmcnt(0)" ::: "memory");
  asm volatile("s_barrier" ::: "memory");
  loadB(127, Bf1);

  asm volatile("s_waitcnt vmcnt(4)" ::: "memory");
  asm volatile("s_barrier" ::: "memory");
  compute(2, Bf0);  // 126
  asm volatile("s_waitcnt lgkmcnt(0)" ::: "memory");
  asm volatile("s_barrier" ::: "memory");

  asm volatile("s_waitcnt vmcnt(0)" ::: "memory");
  asm volatile("s_barrier" ::: "memory");
  compute(3, Bf1);  // 127

  // fused epilogue: out = x + s*(relu(z) - x)
#pragma unroll
  for (int mi = 0; mi < 2; ++mi)
#pragma unroll
    for (int ni = 0; ni < 2; ++ni) {
      f32x4 z = acc[mi][ni];
      int n = w * 32 + ni * 16 + lr;
#pragma unroll
      for (int i = 0; i < 4; ++i) {
        int m = m0 + mi * 16 + lq * 4 + i;
        float x = X[m * 256 + n];
        float sv = s[m];
        out[m * 256 + n] = x + sv * (fmaxf(z[i], 0.f) - x);
      }
    }
}

extern "C" void kernel_launch(void* const* d_in, const int* in_sizes, int n_in,
                              void* d_out, int out_size, void* d_ws, size_t ws_size,
                              hipStream_t stream) {
  const float* X = (const float*)d_in[0];
  const float* A = (const float*)d_in[1];
  const float* wg = (const float*)d_in[2];
  const float* wl = (const float*)d_in[3];
  const float* W = (const float*)d_in[4];
  float* out = (float*)d_out;

  // ws: XWT2 bf16 frag-layout 4 MiB, WT bf16 128 KiB, s f32 32 KiB
  unsigned short* XWT2 = (unsigned short*)d_ws;
  unsigned short* WT = (unsigned short*)((char*)d_ws + 4194304);
  float* s = (float*)((char*)d_ws + 4194304 + 131072);

  prep_kernel<<<256, 256, 0, stream>>>(W, wg, wl, WT, s);
  gemm_xw<<<512, 256, 0, stream>>>(X, WT, XWT2);
  gemm_main<<<256, 512, 0, stream>>>(A, XWT2, X, s, out);
}

// Round 6
// 119.668 us; speedup vs baseline: 2.2022x; 1.0704x over previous
//
#include <hip/hip_runtime.h>
#include <hip/hip_bf16.h>

// out = X + s*(relu(A_hat @ (X @ W_agg)) - X), s = sigmoid(wg)*sigmoid(wl)
// X[8192,256] f32, A_hat[8192,8192] f32, W[256,256] f32. Out f32 [8192,256].
// Round 6: K-split. Grid 512 = 2 blocks/CU (block = (m-tile, k-half)); per-CU
// byte totals conserved but the two blocks' vmem/LDS/MFMA phases interleave,
// hiding the serialized ~930ns/iter critical path of round 5. f32 partials in
// ws; tiny finalize kernel applies relu + xi-mix. B-frags stay global->VGPR
// from the L2-resident XWT2 (MFMA-frag layout); LDS holds only A (4x8KB ring).

typedef __attribute__((ext_vector_type(4))) float f32x4;
typedef __attribute__((ext_vector_type(8))) __bf16 bf16x8;

#define GLOBAL_AS __attribute__((address_space(1)))
#define LDS_AS __attribute__((address_space(3)))

static __device__ __forceinline__ void gload16(const void* g, void* l) {
  __builtin_amdgcn_global_load_lds((const GLOBAL_AS void*)g, (LDS_AS void*)l, 16, 0, 0);
}
// A stream: NT(bit1)|SC1(bit4) -> protect L2 residency of B/X/out.
static __device__ __forceinline__ void gload16_stream(const void* g, void* l) {
  __builtin_amdgcn_global_load_lds((const GLOBAL_AS void*)g, (LDS_AS void*)l, 16, 0, 0x12);
}

static __device__ __forceinline__ unsigned short f2bf_bits(float f) {
  __bf16 h = (__bf16)f;
  return __builtin_bit_cast(unsigned short, h);
}

// ---------------- prep: s vector + W^T (bf16, tiled [k/32][n=256][32]) -------------
__global__ void prep_kernel(const float* __restrict__ W,
                            const float* __restrict__ wg,
                            const float* __restrict__ wl,
                            unsigned short* __restrict__ WT,  // [8][256][32] bf16
                            float* __restrict__ s) {
  int tid = blockIdx.x * 256 + threadIdx.x;  // 0..65535
  int k = tid >> 8, n = tid & 255;
  float w = W[tid];  // W[k][n]
  int kt = k >> 5, kloc = k & 31;
  WT[kt * 8192 + n * 32 + kloc] = f2bf_bits(w);
  if (tid < 8192) {
    float sg = 1.0f / (1.0f + expf(-wg[0]));
    float sl = 1.0f / (1.0f + expf(-wl[tid]));
    s[tid] = sg * sl;
  }
}

// ---------------- gemm0: XW = X @ W  ->  XWT2 in MFMA B-frag layout ----------------
// XWT2 block for (c=k/64, w=n/32, kk=(k>>5)&1, ni=(n>>4)&1): 64 lanes x 16B, where
// lane = (n&15) + 16*((k>>3)&3), holding 8 consecutive bf16 along k.
__global__ __launch_bounds__(256, 2) void gemm_xw(
    const float* __restrict__ X,              // [8192][256]
    const unsigned short* __restrict__ WT,    // tiled [8][256][32]
    unsigned short* __restrict__ XWT2) {      // 4 MiB, frag-layout
  __shared__ float As[2][32 * 32];
  __shared__ unsigned short Bs[2][128 * 32];

  const int bm = blockIdx.x & 255;
  const int bn = blockIdx.x >> 8;
  const int m0 = bm * 32;
  const int tid = threadIdx.x;
  const int w = tid >> 6;
  const int l = tid & 63;
  const int lr = l & 15;
  const int lq = l >> 4;

  const int pA = w * 1024 + l * 16;
  const int rA = pA >> 7;
  const int qA = (pA >> 4) & 7;
  const int ssA = qA ^ (rA & 7);
  const char* Asrc0 = (const char*)X + (size_t)(m0 + rA) * 1024 + ssA * 16;
  const char* Bsrc0 = (const char*)WT + bn * 8192 + w * 2048 + l * 16;

  f32x4 acc[2][2];
#pragma unroll
  for (int i = 0; i < 2; ++i)
#pragma unroll
    for (int j = 0; j < 2; ++j) acc[i][j] = (f32x4){0.f, 0.f, 0.f, 0.f};

  auto stage = [&](int t, int buf) {
    gload16(Asrc0 + (size_t)t * 128, (char*)&As[buf][0] + w * 1024);
    const char* bs = Bsrc0 + (size_t)t * 16384;
    gload16(bs, (char*)&Bs[buf][0] + w * 2048);
    gload16(bs + 1024, (char*)&Bs[buf][0] + w * 2048 + 1024);
  };

  auto compute = [&](int buf) {
    bf16x8 af[2];
#pragma unroll
    for (int mi = 0; mi < 2; ++mi) {
      int r = mi * 16 + lr;
      const float* ap = &As[buf][r * 32];
      int s0 = (2 * lq) ^ (r & 7);
      int s1 = (2 * lq + 1) ^ (r & 7);
      f32x4 a0 = *(const f32x4*)(ap + s0 * 4);
      f32x4 a1 = *(const f32x4*)(ap + s1 * 4);
      bf16x8 v;
      v[0] = (__bf16)a0.x; v[1] = (__bf16)a0.y; v[2] = (__bf16)a0.z; v[3] = (__bf16)a0.w;
      v[4] = (__bf16)a1.x; v[5] = (__bf16)a1.y; v[6] = (__bf16)a1.z; v[7] = (__bf16)a1.w;
      af[mi] = v;
    }
    bf16x8 bfr[2];
#pragma unroll
    for (int ni = 0; ni < 2; ++ni) {
      int row = w * 32 + ni * 16 + lr;
      bfr[ni] = *(const bf16x8*)(&Bs[buf][row * 32 + lq * 8]);
    }
#pragma unroll
    for (int mi = 0; mi < 2; ++mi)
#pragma unroll
      for (int ni = 0; ni < 2; ++ni)
        acc[mi][ni] = __builtin_amdgcn_mfma_f32_16x16x32_bf16(af[mi], bfr[ni], acc[mi][ni], 0, 0, 0);
  };

  stage(0, 0);
  __syncthreads();
  for (int t = 0; t < 8; ++t) {
    int cur = t & 1;
    if (t + 1 < 8) stage(t + 1, cur ^ 1);
    compute(cur);
    __syncthreads();
  }

  // epilogue -> XWT2 frag layout. k (main-GEMM) = bm*32 + mi*16 + lq*4 + i
#pragma unroll
  for (int mi = 0; mi < 2; ++mi)
#pragma unroll
    for (int ni2 = 0; ni2 < 2; ++ni2) {
      f32x4 z = acc[mi][ni2];
      int n = bn * 128 + w * 32 + ni2 * 16 + lr;
      int k = bm * 32 + mi * 16 + lq * 4;
      int c = k >> 6;
      int kk = (k >> 5) & 1;
      int ni = (n >> 4) & 1;
      int wp = n >> 5;
      int lane2 = (n & 15) + 16 * ((k >> 3) & 3);
      int j0 = k & 7;  // 0 or 4
      size_t off = (((size_t)c * 8 + wp) * 4 + kk * 2 + ni) * 512 + lane2 * 8 + j0;
      ushort4 u;
      u.x = f2bf_bits(z[0]); u.y = f2bf_bits(z[1]);
      u.z = f2bf_bits(z[2]); u.w = f2bf_bits(z[3]);
      *(ushort4*)(XWT2 + off) = u;
    }
}

// ---------------- gemm1: P = A_hat[:, khalf] @ XW[khalf]  (or full, fused) --------
// BM=32, BN=256, BK=64, 512 threads = 8 waves (wave w: 32m x 32n at n0=w*32).
// SPLIT: grid 512, block b -> m0=(b>>1)*32, k0=(b&1)*4096, NT=64 iters, f32
// partial to P[b&1]. !SPLIT: grid 256, NT=128, fused epilogue (fallback).
template <int NT, bool SPLIT>
__global__ __launch_bounds__(512, 4) void gemm_main(
    const float* __restrict__ A,              // [8192][8192]
    const unsigned short* __restrict__ B2,    // XWT2 frag layout
    const float* __restrict__ X,              // [8192][256]
    const float* __restrict__ s,              // [8192]
    float* __restrict__ out,                  // [8192][256]
    float* __restrict__ P) {                  // [2][8192][256] partials (SPLIT)
  __shared__ float As[4][32 * 64];  // 4 x 8 KB ring, rows 256B, 16-slot XOR swizzle

  const int bid = blockIdx.x;
  const int m0 = SPLIT ? (bid >> 1) * 32 : bid * 32;
  const int khalf = SPLIT ? (bid & 1) : 0;
  const int tid = threadIdx.x;  // 0..511
  const int w = tid >> 6;       // 0..7
  const int l = tid & 63;
  const int lr = l & 15;
  const int lq = l >> 4;

  // A staging: thread t -> LDS byte t*16 (row r=t>>4, slot q=t&15).
  // LDS promise: row r slot q holds global k-slot q ^ (r&15).
  const int rA = tid >> 4;
  const int qA = tid & 15;
  const int sqA = qA ^ (rA & 15);
  const char* Asrc =
      (const char*)A + (size_t)(m0 + rA) * 32768 + (size_t)khalf * 16384 + sqA * 16;
  const char* Bbase =
      (const char*)B2 + (size_t)khalf * 64 * 32768 + (size_t)w * 4096 + (size_t)l * 16;

  f32x4 acc[2][2];
#pragma unroll
  for (int i = 0; i < 2; ++i)
#pragma unroll
    for (int j = 0; j < 2; ++j) acc[i][j] = (f32x4){0.f, 0.f, 0.f, 0.f};

  struct BF { bf16x8 a, b, c, d; };  // (kk,ni) = (0,0),(0,1),(1,0),(1,1)
  BF Bf0, Bf1;

  auto stageA = [&](int h, int buf) {
    gload16_stream(Asrc + (size_t)h * 256, (char*)&As[buf][0] + w * 1024);
  };
  auto loadB = [&](int h, BF& f) {
    const char* p = Bbase + (size_t)h * 32768;
    f.a = *(const bf16x8*)(p);
    f.b = *(const bf16x8*)(p + 1024);
    f.c = *(const bf16x8*)(p + 2048);
    f.d = *(const bf16x8*)(p + 3072);
  };

  auto compute = [&](int buf, const BF& f) {
    const char* Ab = (const char*)&As[buf][0];
    bf16x8 af[2][2];  // [kk][mi]
#pragma unroll
    for (int kk = 0; kk < 2; ++kk)
#pragma unroll
      for (int mi = 0; mi < 2; ++mi) {
        int r = mi * 16 + lr;
        int s0 = (kk * 8 + 2 * lq) ^ (r & 15);
        int s1 = ((kk * 8 + 2 * lq) + 1) ^ (r & 15);
        f32x4 a0 = *(const f32x4*)(Ab + r * 256 + s0 * 16);
        f32x4 a1 = *(const f32x4*)(Ab + r * 256 + s1 * 16);
        bf16x8 v;
        v[0] = (__bf16)a0.x; v[1] = (__bf16)a0.y; v[2] = (__bf16)a0.z; v[3] = (__bf16)a0.w;
        v[4] = (__bf16)a1.x; v[5] = (__bf16)a1.y; v[6] = (__bf16)a1.z; v[7] = (__bf16)a1.w;
        af[kk][mi] = v;
      }
    acc[0][0] = __builtin_amdgcn_mfma_f32_16x16x32_bf16(af[0][0], f.a, acc[0][0], 0, 0, 0);
    acc[0][1] = __builtin_amdgcn_mfma_f32_16x16x32_bf16(af[0][0], f.b, acc[0][1], 0, 0, 0);
    acc[1][0] = __builtin_amdgcn_mfma_f32_16x16x32_bf16(af[0][1], f.a, acc[1][0], 0, 0, 0);
    acc[1][1] = __builtin_amdgcn_mfma_f32_16x16x32_bf16(af[0][1], f.b, acc[1][1], 0, 0, 0);
    acc[0][0] = __builtin_amdgcn_mfma_f32_16x16x32_bf16(af[1][0], f.c, acc[0][0], 0, 0, 0);
    acc[0][1] = __builtin_amdgcn_mfma_f32_16x16x32_bf16(af[1][0], f.d, acc[0][1], 0, 0, 0);
    acc[1][0] = __builtin_amdgcn_mfma_f32_16x16x32_bf16(af[1][1], f.c, acc[1][0], 0, 0, 0);
    acc[1][1] = __builtin_amdgcn_mfma_f32_16x16x32_bf16(af[1][1], f.d, acc[1][1], 0, 0, 0);
  };

  // prologue FIFO: A0, B0x4, A1, B1x4, A2, A3  (12 vmem ops)
  stageA(0, 0);
  loadB(0, Bf0);
  stageA(1, 1);
  loadB(1, Bf1);
  stageA(2, 2);
  stageA(3, 3);

  // steady state: entering iter h, FIFO = [B(h)x4, A(h+2), B(h+1)x4, A(h+3)];
  // vmcnt(6) forces B(h) (and all older, incl A(h)) complete.
  for (int h = 0; h < NT - 4; h += 2) {
    asm volatile("s_waitcnt vmcnt(6)" ::: "memory");
    asm volatile("s_barrier" ::: "memory");
    compute(h & 3, Bf0);
    asm volatile("s_waitcnt lgkmcnt(0)" ::: "memory");
    asm volatile("s_barrier" ::: "memory");
    loadB(h + 2, Bf0);
    stageA(h + 4, h & 3);

    asm volatile("s_waitcnt vmcnt(6)" ::: "memory");
    asm volatile("s_barrier" ::: "memory");
    compute((h + 1) & 3, Bf1);
    asm volatile("s_waitcnt lgkmcnt(0)" ::: "memory");
    asm volatile("s_barrier" ::: "memory");
    loadB(h + 3, Bf1);
    stageA(h + 5, (h + 1) & 3);
  }
  // tail: iters NT-4..NT-1 ((NT-4)&3 == 0 for NT in {64,128})
  asm volatile("s_waitcnt vmcnt(6)" ::: "memory");
  asm volatile("s_barrier" ::: "memory");
  compute(0, Bf0);  // NT-4
  asm volatile("s_waitcnt lgkmcnt(0)" ::: "memory");
  asm volatile("s_barrier" ::: "memory");
  loadB(NT - 2, Bf0);

  asm volatile("s_waitcnt vmcnt(5)" ::: "memory");
  asm volatile("s_barrier" ::: "memory");
  compute(1, Bf1);  // NT-3
  asm volatile("s_waitcnt lgkmcnt(0)" ::: "memory");
  asm volatile("s_barrier" ::: "memory");
  loadB(NT - 1, Bf1);

  asm volatile("s_waitcnt vmcnt(4)" ::: "memory");
  asm volatile("s_barrier" ::: "memory");
  compute(2, Bf0);  // NT-2
  asm volatile("s_waitcnt lgkmcnt(0)" ::: "memory");
  asm volatile("s_barrier" ::: "memory");

  asm volatile("s_waitcnt vmcnt(0)" ::: "memory");
  asm volatile("s_barrier" ::: "memory");
  compute(3, Bf1);  // NT-1

  if (SPLIT) {
    // write f32 partial
    float* Pb = P + (size_t)khalf * 8192 * 256;
#pragma unroll
    for (int mi = 0; mi < 2; ++mi)
#pragma unroll
      for (int ni = 0; ni < 2; ++ni) {
        f32x4 z = acc[mi][ni];
        int n = w * 32 + ni * 16 + lr;
#pragma unroll
        for (int i = 0; i < 4; ++i) {
          int m = m0 + mi * 16 + lq * 4 + i;
          Pb[m * 256 + n] = z[i];
        }
      }
  } else {
    // fused epilogue: out = x + s*(relu(z) - x)
#pragma unroll
    for (int mi = 0; mi < 2; ++mi)
#pragma unroll
      for (int ni = 0; ni < 2; ++ni) {
        f32x4 z = acc[mi][ni];
        int n = w * 32 + ni * 16 + lr;
#pragma unroll
        for (int i = 0; i < 4; ++i) {
          int m = m0 + mi * 16 + lq * 4 + i;
          float x = X[m * 256 + n];
          float sv = s[m];
          out[m * 256 + n] = x + sv * (fmaxf(z[i], 0.f) - x);
        }
      }
  }
}

// ---------------- finalize: out = x + s*(relu(p0+p1) - x) --------------------------
__global__ __launch_bounds__(256) void finalize_kernel(
    const float* __restrict__ P,   // [2][8192][256]
    const float* __restrict__ X,
    const float* __restrict__ s,
    float* __restrict__ out) {
  int i = blockIdx.x * 256 + threadIdx.x;  // 0..524287, one f32x4 each
  int m = i >> 6;                          // 64 quads per row
  f32x4 p0 = *(const f32x4*)(P + (size_t)i * 4);
  f32x4 p1 = *(const f32x4*)(P + 2097152 + (size_t)i * 4);
  f32x4 x = *(const f32x4*)(X + (size_t)i * 4);
  float sv = s[m];
  f32x4 o;
#pragma unroll
  for (int j = 0; j < 4; ++j) o[j] = x[j] + sv * (fmaxf(p0[j] + p1[j], 0.f) - x[j]);
  *(f32x4*)(out + (size_t)i * 4) = o;
}

extern "C" void kernel_launch(void* const* d_in, const int* in_sizes, int n_in,
                              void* d_out, int out_size, void* d_ws, size_t ws_size,
                              hipStream_t stream) {
  const float* X = (const float*)d_in[0];
  const float* A = (const float*)d_in[1];
  const float* wg = (const float*)d_in[2];
  const float* wl = (const float*)d_in[3];
  const float* W = (const float*)d_in[4];
  float* out = (float*)d_out;

  // ws: XWT2 4 MiB | WT 128 KiB | s 32 KiB | P 16 MiB  (P only if it fits)
  unsigned short* XWT2 = (unsigned short*)d_ws;
  unsigned short* WT = (unsigned short*)((char*)d_ws + 4194304);
  float* s = (float*)((char*)d_ws + 4194304 + 131072);
  float* P = (float*)((char*)d_ws + 4194304 + 131072 + 32768);

  prep_kernel<<<256, 256, 0, stream>>>(W, wg, wl, WT, s);
  gemm_xw<<<512, 256, 0, stream>>>(X, WT, XWT2);

  const size_t need = 4194304 + 131072 + 32768 + 2u * 8192 * 256 * 4;
  if (ws_size >= need) {
    gemm_main<64, true><<<512, 512, 0, stream>>>(A, XWT2, X, s, out, P);
    finalize_kernel<<<2048, 256, 0, stream>>>(P, X, s, out);
  } else {
    gemm_main<128, false><<<256, 512, 0, stream>>>(A, XWT2, X, s, out, nullptr);
  }
}

// Round 7
// 107.664 us; speedup vs baseline: 2.4477x; 1.1115x over previous
//
#include <hip/hip_runtime.h>
#include <hip/hip_bf16.h>

// out = X + s*(relu(A_hat @ (X @ W_agg)) - X), s = sigmoid(wg)*sigmoid(wl)
// X[8192,256] f32, A_hat[8192,8192] f32, W[256,256] f32. Out f32 [8192,256].
// Round 7: serial-sum reduction. r6 counters validated: per-CU time = HBM-A
// (43us) + L2-B (30us) + LDS (30us) serialized. This round: A staged as bf16
// via regs (LDS 9.2->2.6 MB/CU), BM=128 (B-L2 4->2 MB/CU), ksplit=8 with
// kseg==XCD (each XCD L2 holds one 512KB B slice), bf16 partials + finalize.

typedef __attribute__((ext_vector_type(4))) float f32x4;
typedef __attribute__((ext_vector_type(8))) __bf16 bf16x8;
typedef __attribute__((ext_vector_type(8))) unsigned short u16x8;

#define GLOBAL_AS __attribute__((address_space(1)))
#define LDS_AS __attribute__((address_space(3)))

static __device__ __forceinline__ void gload16(const void* g, void* l) {
  __builtin_amdgcn_global_load_lds((const GLOBAL_AS void*)g, (LDS_AS void*)l, 16, 0, 0);
}
static __device__ __forceinline__ void gload16_stream(const void* g, void* l) {
  __builtin_amdgcn_global_load_lds((const GLOBAL_AS void*)g, (LDS_AS void*)l, 16, 0, 0x12);
}

static __device__ __forceinline__ unsigned short f2bf_bits(float f) {
  __bf16 h = (__bf16)f;
  return __builtin_bit_cast(unsigned short, h);
}
static __device__ __forceinline__ float bf2f(unsigned short u) {
  return __builtin_bit_cast(float, (unsigned)u << 16);
}

// ---------------- prep: s vector + W^T (bf16, tiled [k/32][n=256][32]) -------------
__global__ void prep_kernel(const float* __restrict__ W,
                            const float* __restrict__ wg,
                            const float* __restrict__ wl,
                            unsigned short* __restrict__ WT,  // [8][256][32] bf16
                            float* __restrict__ s) {
  int tid = blockIdx.x * 256 + threadIdx.x;  // 0..65535
  int k = tid >> 8, n = tid & 255;
  float w = W[tid];  // W[k][n]
  int kt = k >> 5, kloc = k & 31;
  WT[kt * 8192 + n * 32 + kloc] = f2bf_bits(w);
  if (tid < 8192) {
    float sg = 1.0f / (1.0f + expf(-wg[0]));
    float sl = 1.0f / (1.0f + expf(-wl[tid]));
    s[tid] = sg * sl;
  }
}

// ---------------- gemm0: XW = X @ W  ->  XWT2 in MFMA B-frag layout ----------------
// XWT2 block for (c=k/64, wp=n/32, kk=(k>>5)&1, ni=(n>>4)&1): 64 lanes x 16B, lane
// = (n&15) + 16*((k>>3)&3), holding 8 consecutive bf16 along k.
__global__ __launch_bounds__(256, 2) void gemm_xw(
    const float* __restrict__ X,              // [8192][256]
    const unsigned short* __restrict__ WT,    // tiled [8][256][32]
    unsigned short* __restrict__ XWT2) {      // 4 MiB, frag-layout
  __shared__ float As[2][32 * 32];
  __shared__ unsigned short Bs[2][128 * 32];

  const int bm = blockIdx.x & 255;
  const int bn = blockIdx.x >> 8;
  const int m0 = bm * 32;
  const int tid = threadIdx.x;
  const int w = tid >> 6;
  const int l = tid & 63;
  const int lr = l & 15;
  const int lq = l >> 4;

  const int pA = w * 1024 + l * 16;
  const int rA = pA >> 7;
  const int qA = (pA >> 4) & 7;
  const int ssA = qA ^ (rA & 7);
  const char* Asrc0 = (const char*)X + (size_t)(m0 + rA) * 1024 + ssA * 16;
  const char* Bsrc0 = (const char*)WT + bn * 8192 + w * 2048 + l * 16;

  f32x4 acc[2][2];
#pragma unroll
  for (int i = 0; i < 2; ++i)
#pragma unroll
    for (int j = 0; j < 2; ++j) acc[i][j] = (f32x4){0.f, 0.f, 0.f, 0.f};

  auto stage = [&](int t, int buf) {
    gload16(Asrc0 + (size_t)t * 128, (char*)&As[buf][0] + w * 1024);
    const char* bs = Bsrc0 + (size_t)t * 16384;
    gload16(bs, (char*)&Bs[buf][0] + w * 2048);
    gload16(bs + 1024, (char*)&Bs[buf][0] + w * 2048 + 1024);
  };

  auto compute = [&](int buf) {
    bf16x8 af[2];
#pragma unroll
    for (int mi = 0; mi < 2; ++mi) {
      int r = mi * 16 + lr;
      const float* ap = &As[buf][r * 32];
      int s0 = (2 * lq) ^ (r & 7);
      int s1 = (2 * lq + 1) ^ (r & 7);
      f32x4 a0 = *(const f32x4*)(ap + s0 * 4);
      f32x4 a1 = *(const f32x4*)(ap + s1 * 4);
      bf16x8 v;
      v[0] = (__bf16)a0.x; v[1] = (__bf16)a0.y; v[2] = (__bf16)a0.z; v[3] = (__bf16)a0.w;
      v[4] = (__bf16)a1.x; v[5] = (__bf16)a1.y; v[6] = (__bf16)a1.z; v[7] = (__bf16)a1.w;
      af[mi] = v;
    }
    bf16x8 bfr[2];
#pragma unroll
    for (int ni = 0; ni < 2; ++ni) {
      int row = w * 32 + ni * 16 + lr;
      bfr[ni] = *(const bf16x8*)(&Bs[buf][row * 32 + lq * 8]);
    }
#pragma unroll
    for (int mi = 0; mi < 2; ++mi)
#pragma unroll
      for (int ni = 0; ni < 2; ++ni)
        acc[mi][ni] = __builtin_amdgcn_mfma_f32_16x16x32_bf16(af[mi], bfr[ni], acc[mi][ni], 0, 0, 0);
  };

  stage(0, 0);
  __syncthreads();
  for (int t = 0; t < 8; ++t) {
    int cur = t & 1;
    if (t + 1 < 8) stage(t + 1, cur ^ 1);
    compute(cur);
    __syncthreads();
  }

  // epilogue -> XWT2 frag layout. k (main-GEMM contraction) = bm*32 + mi*16 + lq*4
#pragma unroll
  for (int mi = 0; mi < 2; ++mi)
#pragma unroll
    for (int ni2 = 0; ni2 < 2; ++ni2) {
      f32x4 z = acc[mi][ni2];
      int n = bn * 128 + w * 32 + ni2 * 16 + lr;
      int k = bm * 32 + mi * 16 + lq * 4;
      int c = k >> 6;
      int kk = (k >> 5) & 1;
      int ni = (n >> 4) & 1;
      int wp = n >> 5;
      int lane2 = (n & 15) + 16 * ((k >> 3) & 3);
      int j0 = k & 7;  // 0 or 4
      size_t off = (((size_t)c * 8 + wp) * 4 + kk * 2 + ni) * 512 + lane2 * 8 + j0;
      ushort4 u;
      u.x = f2bf_bits(z[0]); u.y = f2bf_bits(z[1]);
      u.z = f2bf_bits(z[2]); u.w = f2bf_bits(z[3]);
      *(ushort4*)(XWT2 + off) = u;
    }
}

// ---------------- gemm_ks8: P[kseg] = A[:, kseg] @ XW[kseg]  (bf16 partials) -------
// BM=128, BN=256, BK=32, ksplit=8. Grid 512 = 2 blocks/CU. 512 thr = 8 waves,
// wave (wm=w>>2, wn=w&3) owns 64m x 64n. A reg-staged f32->bf16 into LDS
// (padded 80B rows, conflict-free). B frags global->VGPR from L2-resident
// XWT2 slice (kseg == XCD id under round-robin dispatch). One barrier/iter;
// vmem waits are compiler-counted (issue-early, wait-late source order).
__global__ __launch_bounds__(512, 4) void gemm_ks8(
    const float* __restrict__ A,              // [8192][8192]
    const unsigned short* __restrict__ B2,    // XWT2 frag layout
    unsigned short* __restrict__ P) {         // [8][8192][256] bf16 partials
  __shared__ unsigned short Al[2][128 * 40];  // 2 x 10KB, rows padded to 40 ushorts

  const int bid = blockIdx.x;
  const int mtile = bid >> 3, kseg = bid & 7;
  const int m0 = mtile * 128;
  const int tid = threadIdx.x;  // 0..511
  const int w = tid >> 6, l = tid & 63;
  const int lr = l & 15, lq = l >> 4;
  const int wm = w >> 2, wn = w & 3;

  // staging map: thread -> row r=tid>>2, k-chunk c4=tid&3 (8 consecutive floats)
  const int r = tid >> 2, c4 = tid & 3;
  const float* gA = A + (size_t)(m0 + r) * 8192 + kseg * 1024 + c4 * 8;
  const int woff = r * 40 + c4 * 8;  // ushort index within a buffer

  // B: frag base. block idx = (c*8 + wp)*4 + kk*2 + niL, 512 ushorts each.
  const unsigned short* Bbase = B2 + (size_t)kseg * 262144 + wn * 4096 + l * 8;

  f32x4 acc[4][4];
#pragma unroll
  for (int i = 0; i < 4; ++i)
#pragma unroll
    for (int j = 0; j < 4; ++j) acc[i][j] = (f32x4){0.f, 0.f, 0.f, 0.f};

  f32x4 sa0, sa1;  // staged A regs (A(h+1) in flight)
  bf16x8 Bf0, Bf1, Bf2, Bf3;

  auto loadA = [&](int h) {
    sa0 = *(const f32x4*)(gA + h * 32);
    sa1 = *(const f32x4*)(gA + h * 32 + 4);
  };
  auto writeA = [&](int h) {  // cvt + ds_write A(h) -> Al[h&1]
    bf16x8 b;
    b[0] = (__bf16)sa0.x; b[1] = (__bf16)sa0.y; b[2] = (__bf16)sa0.z; b[3] = (__bf16)sa0.w;
    b[4] = (__bf16)sa1.x; b[5] = (__bf16)sa1.y; b[6] = (__bf16)sa1.z; b[7] = (__bf16)sa1.w;
    *(bf16x8*)(&Al[h & 1][woff]) = b;
  };
  auto loadB = [&](int h) {
    const unsigned short* p = Bbase + (h >> 1) * 16384 + (h & 1) * 1024;
    Bf0 = *(const bf16x8*)(p);
    Bf1 = *(const bf16x8*)(p + 512);
    Bf2 = *(const bf16x8*)(p + 2048);
    Bf3 = *(const bf16x8*)(p + 2560);
  };
  auto compute = [&](int h) {
    const unsigned short* Ab = &Al[h & 1][0];
#pragma unroll
    for (int mi = 0; mi < 4; ++mi) {
      int R = wm * 64 + mi * 16 + lr;
      bf16x8 af = *(const bf16x8*)(Ab + R * 40 + lq * 8);
      acc[mi][0] = __builtin_amdgcn_mfma_f32_16x16x32_bf16(af, Bf0, acc[mi][0], 0, 0, 0);
      acc[mi][1] = __builtin_amdgcn_mfma_f32_16x16x32_bf16(af, Bf1, acc[mi][1], 0, 0, 0);
      acc[mi][2] = __builtin_amdgcn_mfma_f32_16x16x32_bf16(af, Bf2, acc[mi][2], 0, 0, 0);
      acc[mi][3] = __builtin_amdgcn_mfma_f32_16x16x32_bf16(af, Bf3, acc[mi][3], 0, 0, 0);
    }
  };

  // prologue: A(0) staged+written, B(0)+A(1) in flight
  loadA(0);
  writeA(0);
  loadB(0);
  loadA(1);
  asm volatile("s_waitcnt lgkmcnt(0)" ::: "memory");
  asm volatile("s_barrier" ::: "memory");

  for (int h = 0; h < 31; ++h) {
    compute(h);          // compiler waits vmcnt for Bf use (A(h+1) stays in flight)
    loadB(h + 1);        // issue next B (Bf regs free after compute)
    writeA(h + 1);       // compiler waits vmcnt(0-ish) for sa, then ds_write
    if (h < 30) loadA(h + 2);
    asm volatile("s_waitcnt lgkmcnt(0)" ::: "memory");
    asm volatile("s_barrier" ::: "memory");
  }
  compute(31);

  // epilogue: bf16 partial P[kseg][m][n]
  unsigned short* Pb = P + (size_t)kseg * (8192 * 256);
#pragma unroll
  for (int mi = 0; mi < 4; ++mi)
#pragma unroll
    for (int ni = 0; ni < 4; ++ni) {
      f32x4 z = acc[mi][ni];
      int n = wn * 64 + ni * 16 + lr;
#pragma unroll
      for (int i = 0; i < 4; ++i) {
        int m = m0 + wm * 64 + mi * 16 + lq * 4 + i;
        Pb[(size_t)m * 256 + n] = f2bf_bits(z[i]);
      }
    }
}

// ---------------- finalize8: out = x + s*(relu(sum P) - x) -------------------------
__global__ __launch_bounds__(256) void finalize8(
    const unsigned short* __restrict__ P,   // [8][8192][256] bf16
    const float* __restrict__ X,
    const float* __restrict__ s,
    float* __restrict__ out) {
  int i = blockIdx.x * 256 + threadIdx.x;  // 0..262143, 8 n-values each
  int m = i >> 5;
  float acc[8] = {0.f, 0.f, 0.f, 0.f, 0.f, 0.f, 0.f, 0.f};
#pragma unroll
  for (int ks = 0; ks < 8; ++ks) {
    u16x8 v = *(const u16x8*)(P + (size_t)ks * 2097152 + (size_t)i * 8);
#pragma unroll
    for (int j = 0; j < 8; ++j) acc[j] += bf2f(v[j]);
  }
  float sv = s[m];
  f32x4 x0 = *(const f32x4*)(X + (size_t)i * 8);
  f32x4 x1 = *(const f32x4*)(X + (size_t)i * 8 + 4);
  f32x4 o0, o1;
#pragma unroll
  for (int j = 0; j < 4; ++j) {
    o0[j] = x0[j] + sv * (fmaxf(acc[j], 0.f) - x0[j]);
    o1[j] = x1[j] + sv * (fmaxf(acc[4 + j], 0.f) - x1[j]);
  }
  *(f32x4*)(out + (size_t)i * 8) = o0;
  *(f32x4*)(out + (size_t)i * 8 + 4) = o1;
}

// ================= fallback path (round-6 kernels, unchanged) ======================
template <int NT, bool SPLIT>
__global__ __launch_bounds__(512, 4) void gemm_main(
    const float* __restrict__ A,
    const unsigned short* __restrict__ B2,
    const float* __restrict__ X,
    const float* __restrict__ s,
    float* __restrict__ out,
    float* __restrict__ P) {
  __shared__ float As[4][32 * 64];

  const int bid = blockIdx.x;
  const int m0 = SPLIT ? (bid >> 1) * 32 : bid * 32;
  const int khalf = SPLIT ? (bid & 1) : 0;
  const int tid = threadIdx.x;
  const int w = tid >> 6;
  const int l = tid & 63;
  const int lr = l & 15;
  const int lq = l >> 4;

  const int rA = tid >> 4;
  const int qA = tid & 15;
  const int sqA = qA ^ (rA & 15);
  const char* Asrc =
      (const char*)A + (size_t)(m0 + rA) * 32768 + (size_t)khalf * 16384 + sqA * 16;
  const char* Bbase =
      (const char*)B2 + (size_t)khalf * 64 * 32768 + (size_t)w * 4096 + (size_t)l * 16;

  f32x4 acc[2][2];
#pragma unroll
  for (int i = 0; i < 2; ++i)
#pragma unroll
    for (int j = 0; j < 2; ++j) acc[i][j] = (f32x4){0.f, 0.f, 0.f, 0.f};

  struct BF { bf16x8 a, b, c, d; };
  BF Bf0, Bf1;

  auto stageA = [&](int h, int buf) {
    gload16_stream(Asrc + (size_t)h * 256, (char*)&As[buf][0] + w * 1024);
  };
  auto loadB = [&](int h, BF& f) {
    const char* p = Bbase + (size_t)h * 32768;
    f.a = *(const bf16x8*)(p);
    f.b = *(const bf16x8*)(p + 1024);
    f.c = *(const bf16x8*)(p + 2048);
    f.d = *(const bf16x8*)(p + 3072);
  };

  auto compute = [&](int buf, const BF& f) {
    const char* Ab = (const char*)&As[buf][0];
    bf16x8 af[2][2];
#pragma unroll
    for (int kk = 0; kk < 2; ++kk)
#pragma unroll
      for (int mi = 0; mi < 2; ++mi) {
        int rr = mi * 16 + lr;
        int s0 = (kk * 8 + 2 * lq) ^ (rr & 15);
        int s1 = ((kk * 8 + 2 * lq) + 1) ^ (rr & 15);
        f32x4 a0 = *(const f32x4*)(Ab + rr * 256 + s0 * 16);
        f32x4 a1 = *(const f32x4*)(Ab + rr * 256 + s1 * 16);
        bf16x8 v;
        v[0] = (__bf16)a0.x; v[1] = (__bf16)a0.y; v[2] = (__bf16)a0.z; v[3] = (__bf16)a0.w;
        v[4] = (__bf16)a1.x; v[5] = (__bf16)a1.y; v[6] = (__bf16)a1.z; v[7] = (__bf16)a1.w;
        af[kk][mi] = v;
      }
    acc[0][0] = __builtin_amdgcn_mfma_f32_16x16x32_bf16(af[0][0], f.a, acc[0][0], 0, 0, 0);
    acc[0][1] = __builtin_amdgcn_mfma_f32_16x16x32_bf16(af[0][0], f.b, acc[0][1], 0, 0, 0);
    acc[1][0] = __builtin_amdgcn_mfma_f32_16x16x32_bf16(af[0][1], f.a, acc[1][0], 0, 0, 0);
    acc[1][1] = __builtin_amdgcn_mfma_f32_16x16x32_bf16(af[0][1], f.b, acc[1][1], 0, 0, 0);
    acc[0][0] = __builtin_amdgcn_mfma_f32_16x16x32_bf16(af[1][0], f.c, acc[0][0], 0, 0, 0);
    acc[0][1] = __builtin_amdgcn_mfma_f32_16x16x32_bf16(af[1][0], f.d, acc[0][1], 0, 0, 0);
    acc[1][0] = __builtin_amdgcn_mfma_f32_16x16x32_bf16(af[1][1], f.c, acc[1][0], 0, 0, 0);
    acc[1][1] = __builtin_amdgcn_mfma_f32_16x16x32_bf16(af[1][1], f.d, acc[1][1], 0, 0, 0);
  };

  stageA(0, 0);
  loadB(0, Bf0);
  stageA(1, 1);
  loadB(1, Bf1);
  stageA(2, 2);
  stageA(3, 3);

  for (int h = 0; h < NT - 4; h += 2) {
    asm volatile("s_waitcnt vmcnt(6)" ::: "memory");
    asm volatile("s_barrier" ::: "memory");
    compute(h & 3, Bf0);
    asm volatile("s_waitcnt lgkmcnt(0)" ::: "memory");
    asm volatile("s_barrier" ::: "memory");
    loadB(h + 2, Bf0);
    stageA(h + 4, h & 3);

    asm volatile("s_waitcnt vmcnt(6)" ::: "memory");
    asm volatile("s_barrier" ::: "memory");
    compute((h + 1) & 3, Bf1);
    asm volatile("s_waitcnt lgkmcnt(0)" ::: "memory");
    asm volatile("s_barrier" ::: "memory");
    loadB(h + 3, Bf1);
    stageA(h + 5, (h + 1) & 3);
  }
  asm volatile("s_waitcnt vmcnt(6)" ::: "memory");
  asm volatile("s_barrier" ::: "memory");
  compute(0, Bf0);
  asm volatile("s_waitcnt lgkmcnt(0)" ::: "memory");
  asm volatile("s_barrier" ::: "memory");
  loadB(NT - 2, Bf0);

  asm volatile("s_waitcnt vmcnt(5)" ::: "memory");
  asm volatile("s_barrier" ::: "memory");
  compute(1, Bf1);
  asm volatile("s_waitcnt lgkmcnt(0)" ::: "memory");
  asm volatile("s_barrier" ::: "memory");
  loadB(NT - 1, Bf1);

  asm volatile("s_waitcnt vmcnt(4)" ::: "memory");
  asm volatile("s_barrier" ::: "memory");
  compute(2, Bf0);
  asm volatile("s_waitcnt lgkmcnt(0)" ::: "memory");
  asm volatile("s_barrier" ::: "memory");

  asm volatile("s_waitcnt vmcnt(0)" ::: "memory");
  asm volatile("s_barrier" ::: "memory");
  compute(3, Bf1);

  if (SPLIT) {
    float* Pb = P + (size_t)khalf * 8192 * 256;
#pragma unroll
    for (int mi = 0; mi < 2; ++mi)
#pragma unroll
      for (int ni = 0; ni < 2; ++ni) {
        f32x4 z = acc[mi][ni];
        int n = w * 32 + ni * 16 + lr;
#pragma unroll
        for (int i = 0; i < 4; ++i) {
          int m = m0 + mi * 16 + lq * 4 + i;
          Pb[m * 256 + n] = z[i];
        }
      }
  } else {
#pragma unroll
    for (int mi = 0; mi < 2; ++mi)
#pragma unroll
      for (int ni = 0; ni < 2; ++ni) {
        f32x4 z = acc[mi][ni];
        int n = w * 32 + ni * 16 + lr;
#pragma unroll
        for (int i = 0; i < 4; ++i) {
          int m = m0 + mi * 16 + lq * 4 + i;
          float x = X[m * 256 + n];
          float sv = s[m];
          out[m * 256 + n] = x + sv * (fmaxf(z[i], 0.f) - x);
        }
      }
  }
}

__global__ __launch_bounds__(256) void finalize_kernel(
    const float* __restrict__ P,
    const float* __restrict__ X,
    const float* __restrict__ s,
    float* __restrict__ out) {
  int i = blockIdx.x * 256 + threadIdx.x;
  int m = i >> 6;
  f32x4 p0 = *(const f32x4*)(P + (size_t)i * 4);
  f32x4 p1 = *(const f32x4*)(P + 2097152 + (size_t)i * 4);
  f32x4 x = *(const f32x4*)(X + (size_t)i * 4);
  float sv = s[m];
  f32x4 o;
#pragma unroll
  for (int j = 0; j < 4; ++j) o[j] = x[j] + sv * (fmaxf(p0[j] + p1[j], 0.f) - x[j]);
  *(f32x4*)(out + (size_t)i * 4) = o;
}

extern "C" void kernel_launch(void* const* d_in, const int* in_sizes, int n_in,
                              void* d_out, int out_size, void* d_ws, size_t ws_size,
                              hipStream_t stream) {
  const float* X = (const float*)d_in[0];
  const float* A = (const float*)d_in[1];
  const float* wg = (const float*)d_in[2];
  const float* wl = (const float*)d_in[3];
  const float* W = (const float*)d_in[4];
  float* out = (float*)d_out;

  // ws: XWT2 4 MiB | WT 128 KiB | s 32 KiB | P (bf16 32 MiB new / f32 16 MiB old)
  unsigned short* XWT2 = (unsigned short*)d_ws;
  unsigned short* WT = (unsigned short*)((char*)d_ws + 4194304);
  float* s = (float*)((char*)d_ws + 4194304 + 131072);
  char* Pbase = (char*)d_ws + 4194304 + 131072 + 32768;

  prep_kernel<<<256, 256, 0, stream>>>(W, wg, wl, WT, s);
  gemm_xw<<<512, 256, 0, stream>>>(X, WT, XWT2);

  const size_t head = 4194304 + 131072 + 32768;
  const size_t need8 = head + (size_t)8 * 8192 * 256 * 2;   // bf16 partials
  const size_t need2 = head + (size_t)2 * 8192 * 256 * 4;   // f32 partials
  if (ws_size >= need8) {
    gemm_ks8<<<512, 512, 0, stream>>>(A, XWT2, (unsigned short*)Pbase);
    finalize8<<<1024, 256, 0, stream>>>((const unsigned short*)Pbase, X, s, out);
  } else if (ws_size >= need2) {
    gemm_main<64, true><<<512, 512, 0, stream>>>(A, XWT2, X, s, out, (float*)Pbase);
    finalize_kernel<<<2048, 256, 0, stream>>>((const float*)Pbase, X, s, out);
  } else {
    gemm_main<128, false><<<256, 512, 0, stream>>>(A, XWT2, X, s, out, nullptr);
  }
}